// Round 1
// baseline (562.004 us; speedup 1.0000x reference)
//
#include <hip/hip_runtime.h>
#include <hip/hip_bf16.h>

#define LNUM 6
#define BATCH 131072

typedef __bf16 bf16x8 __attribute__((ext_vector_type(8)));
typedef float f32x16 __attribute__((ext_vector_type(16)));
typedef float f32x4  __attribute__((ext_vector_type(4)));

// ---------------- ws layout ----------------
// 36 W blocks, each 256x256 bf16 = 131072 B:
// [nh(2)][kk(16)][nti(4)][lane(64)][16B]
//   n = (nh*4+nti)*32 + (l&31), k = kk*16 + (l>>5)*8 + jj
#define WFRAG_BYTES 131072ul
#define W1B1_OFF 4718592ul   // 12 x (256 f32 W1row || 256 f32 B1)
#define BIAS_OFF 4743168ul   // 36 x 256 f32 (B2/B3/B4)
#define W5_OFF   4780032ul   // 12 x 272 f32 (W5 column || B5 || pad)
#define WS_NEEDED 4793088ul

struct PtrPack { const float* p[21]; };

// -------- prep: pack W2/W3/W4 into MFMA fragment order (verified r4-r17) --------
__global__ void prep_w(PtrPack P, unsigned char* __restrict__ ws) {
    int t = blockIdx.x * 256 + threadIdx.x;
    int blk = t >> 13;
    int e8  = t & 8191;
    int nh  = e8 >> 12;
    int kk  = (e8 >> 8) & 15;
    int nti = (e8 >> 6) & 3;
    int l   = e8 & 63;
    int nt = nh * 4 + nti;
    int n  = nt * 32 + (l & 31);
    int k0 = kk * 16 + (l >> 5) * 8;
    int net = blk / 18, rem = blk % 18;
    int i = rem / 3, g = rem % 3;
    const float* src = P.p[3 + g * 2 + net * 10] + i * 65536;
    bf16x8 v;
#pragma unroll
    for (int jj = 0; jj < 8; ++jj) v[jj] = (__bf16)src[(k0 + jj) * 256 + n];
    *(bf16x8*)(ws + (unsigned long)blk * WFRAG_BYTES + (unsigned)e8 * 16) = v;
}

// -------- prep: W1 row / B1, biases, W5 column / B5 (f32, verified) --------
__global__ void prep_small(PtrPack P, unsigned char* __restrict__ ws) {
    int t = blockIdx.x * 256 + threadIdx.x;
    if (t < 6144) {
        int idx = t >> 9, e = t & 511;
        int net = idx / 6, i = idx % 6;
        int j = (i & 1) ? 0 : 1;
        float v;
        if (e < 256) v = P.p[1 + net * 10][i * 512 + j * 256 + e];
        else         v = P.p[2 + net * 10][i * 256 + (e - 256)];
        ((float*)(ws + W1B1_OFF))[t] = v;
    } else if (t < 6144 + 9216) {
        int u = t - 6144;
        int idx = u >> 8, e = u & 255;
        int net = idx / 18, rem = idx % 18, i = rem / 3, g = rem % 3;
        ((float*)(ws + BIAS_OFF))[u] = P.p[4 + g * 2 + net * 10][i * 256 + e];
    } else if (t < 6144 + 9216 + 12 * 272) {
        int u = t - 6144 - 9216;
        int idx = u / 272, e = u % 272;
        int net = idx / 6, i = idx % 6;
        int ud = (i & 1) ? 1 : 0;
        float v = 0.f;
        if (e < 256)      v = P.p[9 + net * 10][i * 512 + e * 2 + ud];
        else if (e == 256) v = P.p[10 + net * 10][i * 2 + ud];
        ((float*)(ws + W5_OFF))[idx * 272 + e] = v;
    }
}

// ---------------- main fused kernel ----------------
// r18 structure: ONE 512-thread block = TWO independent 128-row halves
// (the two previously-separate co-resident blocks), each with its own
// 69632-B LDS region and per-half sense-reversing barriers. An LDS token
// alternates k-loop (MFMA) ownership between halves so one half's VALU
// phases (layer1 / epilogue / layer5 / acc-init) always run under the
// other half's k-loop -> breaks the measured phase-lock convoy
// (MfmaUtil 47%). Per-wave inner code identical to the r11/r16 optimum
// (walls: wider windows spill, smaller tiles lose weight reuse, more
// waves spill). Token is perf-only; correctness rests on hbar() alone.
// Half selection h = popc(wave)&1 puts one wave of each half on every
// SIMD under both round-robin and contiguous wave->SIMD mappings.
#define L_A   0
#define L_Z0  65536
#define L_Z1  66048
#define L_LD  66560
#define L_RED 67072   // [4 waves][128 rows] f32
#define L_OS  69120   // oS[128]
#define HSTRIDE 69632
#define L_SYNC  139264  // u32: [0]=cnt0 [1]=sns0 [2]=cnt1 [3]=sns1 [4]=turn
#define L_TOTAL 139296

__device__ __forceinline__ unsigned pk2(float a, float b) {
    unsigned short ua = __builtin_bit_cast(unsigned short, (__bf16)a);
    unsigned short ub = __builtin_bit_cast(unsigned short, (__bf16)b);
    return (unsigned)ua | ((unsigned)ub << 16);
}

// sense-reversing barrier for the 4 waves of one half (epoch counter form:
// no counter reset -> no reset race). lgkmcnt(0) orders prior ds_writes;
// sched_barrier fences compiler reordering past the spin (guide rule #18).
__device__ __forceinline__ void hbar(unsigned* cnt, unsigned* sns,
                                     unsigned& epoch, int lane) {
    const unsigned target = epoch + 1;
    asm volatile("s_waitcnt lgkmcnt(0)" ::: "memory");
    if (lane == 0) {
        unsigned old = __hip_atomic_fetch_add(cnt, 1u, __ATOMIC_ACQ_REL,
                                              __HIP_MEMORY_SCOPE_WORKGROUP);
        if ((old & 3u) == 3u)
            __hip_atomic_store(sns, target, __ATOMIC_RELEASE,
                               __HIP_MEMORY_SCOPE_WORKGROUP);
    }
    while (__hip_atomic_load(sns, __ATOMIC_ACQUIRE,
                             __HIP_MEMORY_SCOPE_WORKGROUP) != target)
        __builtin_amdgcn_s_sleep(1);
    epoch = target;
    __builtin_amdgcn_sched_barrier(0);
    asm volatile("" ::: "memory");
}

__global__ __launch_bounds__(512, 2) void realnvp_main(
        const float* __restrict__ x, const unsigned char* __restrict__ ws,
        float* __restrict__ out) {
    __shared__ __align__(16) unsigned char lds[L_TOTAL];
    const int tid = threadIdx.x;
    unsigned* const sy = (unsigned*)(lds + L_SYNC);
    if (tid == 0) { sy[0] = 0; sy[1] = 0; sy[2] = 0; sy[3] = 0; sy[4] = 0; }
    __syncthreads();   // only block-wide barrier; everything after is per-half

    const int lane = tid & 63;
    const int wp   = tid >> 6;                       // physical wave 0..7
    const int h    = __builtin_popcount(wp) & 1;     // half: {0,3,5,6} vs {1,2,4,7}
    const int wv   = wp >> 1;                        // logical wave 0..3 in half
    const int ht   = wv * 64 + lane;                 // logical thread 0..255 in half
    const int li = lane & 31, hi = lane >> 5;

    unsigned char* const ldsh = lds + (unsigned)h * HSTRIDE;
    unsigned* const cnt  = sy + 2 * h;
    unsigned* const sns  = sy + 2 * h + 1;
    unsigned* const turn = sy + 4;
    unsigned epoch = 0;

    float* zA  = (float*)(ldsh + L_Z0);
    float* zB  = (float*)(ldsh + L_Z1);
    float* ldt = (float*)(ldsh + L_LD);
    float* red = (float*)(ldsh + L_RED);
    float* oSa = (float*)(ldsh + L_OS);
    const float* w1b1_g = (const float*)(ws + W1B1_OFF);
    const float* bias_g = (const float*)(ws + BIAS_OFF);
    const float* w5_g   = (const float*)(ws + W5_OFF);

    // LDS row addressing: byte(row,kB) = row*512 + (kB ^ ((row&7)<<4));
    // every row this lane touches has row&7 == li&7 -> one swizzle constant
    const unsigned swr = (unsigned)((li & 7) << 4);

    if (ht < 128) {
        float2 xv = ((const float2*)x)[blockIdx.x * 256 + h * 128 + ht];
        zA[ht] = logf(xv.x) - logf(1.f - xv.x);
        zB[ht] = logf(xv.y) - logf(1.f - xv.y);
        ldt[ht] = 0.f;
    }
    hbar(cnt, sns, epoch, lane);

    const int r1row = wv * 32 + li;

#pragma unroll 1
    for (int ii = 0; ii < LNUM; ++ii) {
        const int i = 5 - ii;
#pragma unroll 1
        for (int net = 0; net < 2; ++net) {
            // ---- layer 1: A[row][k] = relu(z*W1[k]+B1[k]); b128 stores ----
            {
                const float* w1 = w1b1_g + (net * 6 + i) * 512;
                const float zj = ((i & 1) ? zA : zB)[r1row];
                unsigned char* rowp = ldsh + L_A + r1row * 512;
#pragma unroll 4
                for (int jj2 = 0; jj2 < 16; ++jj2) {
                    const int k0 = hi * 128 + jj2 * 8;
                    f32x4 w0 = *(const f32x4*)(w1 + k0);
                    f32x4 w1v = *(const f32x4*)(w1 + k0 + 4);
                    f32x4 b0 = *(const f32x4*)(w1 + 256 + k0);
                    f32x4 b1v = *(const f32x4*)(w1 + 256 + k0 + 4);
                    uint4 v;
                    v.x = pk2(fmaxf(zj * w0[0] + b0[0], 0.f), fmaxf(zj * w0[1] + b0[1], 0.f));
                    v.y = pk2(fmaxf(zj * w0[2] + b0[2], 0.f), fmaxf(zj * w0[3] + b0[3], 0.f));
                    v.z = pk2(fmaxf(zj * w1v[0] + b1v[0], 0.f), fmaxf(zj * w1v[1] + b1v[1], 0.f));
                    v.w = pk2(fmaxf(zj * w1v[2] + b1v[2], 0.f), fmaxf(zj * w1v[3] + b1v[3], 0.f));
                    *(uint4*)(rowp + (((unsigned)(k0 * 2)) ^ swr)) = v;
                }
            }
            hbar(cnt, sns, epoch, lane);
#pragma unroll 1
            for (int g = 0; g < 3; ++g) {
                const int blk = (net * 6 + i) * 3 + g;
                const unsigned char* wbase = ws + (unsigned long)blk * WFRAG_BYTES
                        + (unsigned)(wv >> 1) * 65536 + (unsigned)(wv & 1) * 2048
                        + (unsigned)lane * 16;
                const float* biasl = bias_g + blk * 256 + wv * 64;
                const float* w5 = w5_g + (net * 6 + i) * 272;

                f32x16 acc[8];   // [rt*2 + j]: rows rt*32.., n = wv*64 + j*32 ..
#pragma unroll
                for (int j2 = 0; j2 < 2; ++j2)
#pragma unroll
                    for (int q = 0; q < 4; ++q) {
                        f32x4 bb = *(const f32x4*)(biasl + j2 * 32 + q * 8 + hi * 4);
#pragma unroll
                        for (int rt = 0; rt < 4; ++rt) {
                            acc[rt * 2 + j2][4 * q + 0] = bb[0];
                            acc[rt * 2 + j2][4 * q + 1] = bb[1];
                            acc[rt * 2 + j2][4 * q + 2] = bb[2];
                            acc[rt * 2 + j2][4 * q + 3] = bb[3];
                        }
                    }
                // weight ring (global->reg, 3 k-steps deep) + act ping-pong
                bf16x8 wq[3][2];
#pragma unroll
                for (int p = 0; p < 3; ++p) {
                    wq[p][0] = *(const bf16x8*)(wbase + p * 4096);
                    wq[p][1] = *(const bf16x8*)(wbase + p * 4096 + 1024);
                }
                bf16x8 aa[2][4];
#pragma unroll
                for (int rt = 0; rt < 4; ++rt)
                    aa[0][rt] = *(const bf16x8*)(ldsh + L_A + (rt * 32 + li) * 512
                                                 + (((unsigned)(hi * 16)) ^ swr));
                // ---- acquire MFMA-pipe token: halves alternate k-loops so
                // the other half's VALU phases hide under this k-loop.
                // Perf-only (no correctness dependence). ----
                while (__hip_atomic_load(turn, __ATOMIC_ACQUIRE,
                                         __HIP_MEMORY_SCOPE_WORKGROUP) != (unsigned)h)
                    __builtin_amdgcn_s_sleep(1);
                __builtin_amdgcn_sched_barrier(0);
#pragma unroll
                for (int k = 0; k < 16; ++k) {
                    const int cur = k & 1, nxt = cur ^ 1;
                    if (k < 15) {
#pragma unroll
                        for (int rt = 0; rt < 4; ++rt)
                            aa[nxt][rt] = *(const bf16x8*)(ldsh + L_A + (rt * 32 + li) * 512
                                          + (((unsigned)((k + 1) * 32 + hi * 16)) ^ swr));
                    }
                    __builtin_amdgcn_s_setprio(1);
#pragma unroll
                    for (int rt = 0; rt < 4; ++rt) {
                        acc[rt * 2 + 0] = __builtin_amdgcn_mfma_f32_32x32x16_bf16(wq[k % 3][0], aa[cur][rt], acc[rt * 2 + 0], 0, 0, 0);
                        acc[rt * 2 + 1] = __builtin_amdgcn_mfma_f32_32x32x16_bf16(wq[k % 3][1], aa[cur][rt], acc[rt * 2 + 1], 0, 0, 0);
                    }
                    __builtin_amdgcn_s_setprio(0);
                    if (k < 13) {
                        wq[k % 3][0] = *(const bf16x8*)(wbase + (k + 3) * 4096);
                        wq[k % 3][1] = *(const bf16x8*)(wbase + (k + 3) * 4096 + 1024);
                    }
                }
                hbar(cnt, sns, epoch, lane);   // all 4 waves done reading A
                // ---- release token: other half's k-loop may start now ----
                if (ht == 0)
                    __hip_atomic_store(turn, (unsigned)(h ^ 1), __ATOMIC_RELEASE,
                                       __HIP_MEMORY_SCOPE_WORKGROUP);
                if (g < 2) {
                    // epilogue: relu -> bf16 pairs -> in-place A[row][n] writes
#pragma unroll
                    for (int rt = 0; rt < 4; ++rt) {
                        unsigned char* rp = ldsh + L_A + (rt * 32 + li) * 512;
#pragma unroll
                        for (int j2 = 0; j2 < 2; ++j2)
#pragma unroll
                            for (int q = 0; q < 4; ++q) {
                                const f32x16& A = acc[rt * 2 + j2];
                                unsigned lo = pk2(fmaxf(A[4 * q + 0], 0.f), fmaxf(A[4 * q + 1], 0.f));
                                unsigned h2 = pk2(fmaxf(A[4 * q + 2], 0.f), fmaxf(A[4 * q + 3], 0.f));
                                const unsigned nB = (unsigned)((wv * 64 + j2 * 32 + q * 8 + hi * 4) * 2);
                                *(uint2*)(rp + (nB ^ swr)) = make_uint2(lo, h2);
                            }
                    }
                    hbar(cnt, sns, epoch, lane);
                } else {
                    // layer-5 dot over this wave's n-slice, then cross-wave reduce
                    float part[4] = {0.f, 0.f, 0.f, 0.f};
#pragma unroll
                    for (int j2 = 0; j2 < 2; ++j2)
#pragma unroll
                        for (int q = 0; q < 4; ++q) {
                            f32x4 ww = *(const f32x4*)(w5 + wv * 64 + j2 * 32 + q * 8 + hi * 4);
#pragma unroll
                            for (int rt = 0; rt < 4; ++rt)
#pragma unroll
                                for (int c = 0; c < 4; ++c)
                                    part[rt] += fmaxf(acc[rt * 2 + j2][4 * q + c], 0.f) * ww[c];
                        }
#pragma unroll
                    for (int rt = 0; rt < 4; ++rt) part[rt] += __shfl_xor(part[rt], 32);
                    if (hi == 0) {
#pragma unroll
                        for (int rt = 0; rt < 4; ++rt) red[wv * 128 + rt * 32 + li] = part[rt];
                    }
                    hbar(cnt, sns, epoch, lane);
                    if (ht < 128) {
                        const float o = red[ht] + red[128 + ht] + red[256 + ht] + red[384 + ht]
                                        + w5[256];
                        if (net == 0) {
                            oSa[ht] = o;
                        } else {
                            const float s = tanhf(oSa[ht]);
                            const float e = expf(-s);
                            if (i & 1) zB[ht] = (zB[ht] - o) * e;
                            else       zA[ht] = (zA[ht] - o) * e;
                            ldt[ht] -= s;
                        }
                    }
                    hbar(cnt, sns, epoch, lane);
                }
            }
        }
    }
    if (ht < 128) {
        const int row = blockIdx.x * 256 + h * 128 + ht;
        ((float2*)out)[row] = make_float2(1.f / (1.f + expf(-zA[ht])),
                                          1.f / (1.f + expf(-zB[ht])));
        out[2 * BATCH + row] = ldt[ht];
    }
}

extern "C" void kernel_launch(void* const* d_in, const int* in_sizes, int n_in,
                              void* d_out, int out_size, void* d_ws, size_t ws_size,
                              hipStream_t stream) {
    if (ws_size < WS_NEEDED) return;
    PtrPack P;
    for (int k = 0; k < 21; ++k) P.p[k] = (const float*)d_in[k];
    unsigned char* ws = (unsigned char*)d_ws;
    prep_w<<<dim3(1152), dim3(256), 0, stream>>>(P, ws);
    prep_small<<<dim3(73), dim3(256), 0, stream>>>(P, ws);
    realnvp_main<<<dim3(512), dim3(512), 0, stream>>>((const float*)d_in[0], ws, (float*)d_out);
}